// Round 9
// baseline (272.360 us; speedup 1.0000x reference)
//
#include <hip/hip_runtime.h>

// TCM_77464030151162: x(N,128)@w1+b1 -> split 64/64 -> two gathered 3^3 sparse
// convs (27 offsets, 64x64 each, ReLU) -> +2*conv_x residual -> concat@w2+b2 -> +x.
// fp32 wire, bf16 MFMA compute.
// R9: gemm_out FUSED into conv2's epilogue (z: regs -> LDS (C->A layout xform,
// stride 72 pad) -> MFMA vs w2 B-frags straight from global L1; +x skip; fp32 out).
// Kills one ~45us dispatch + z1 round-trip. conv1/gemm_in = R4-exact (proven).
// w2T now stored UNSWIZZLED (read from global, not LDS).

#define N_PTS 100000
#define NBLK128 782 // ceil(100000/128)

typedef __attribute__((ext_vector_type(8))) short frag_ab; // 8 bf16 (4 VGPRs)
typedef __attribute__((ext_vector_type(4))) float f32x4;   // MFMA 16x16 C/D
#define ZFRAG frag_ab{0, 0, 0, 0, 0, 0, 0, 0}

__device__ __forceinline__ unsigned short f2bf(float f) {
  union { float f; unsigned int i; } v; v.f = f;
  unsigned int r = v.i + 0x7fffu + ((v.i >> 16) & 1u); // RNE
  return (unsigned short)(r >> 16);
}
__device__ __forceinline__ float bf2f(unsigned short u) {
  union { unsigned int i; float f; } v; v.i = ((unsigned int)u) << 16; return v.f;
}

// async global->LDS, 16B per lane. LDS dest = wave-uniform base + lane*16 (m104).
__device__ __forceinline__ void gload_lds16(const unsigned short* g, unsigned short* l) {
  __builtin_amdgcn_global_load_lds(
      (const __attribute__((address_space(1))) unsigned int*)g,
      (__attribute__((address_space(3))) unsigned int*)(unsigned int)(size_t)l,
      16, 0, 0);
}

// ---- weight convert+transpose via LDS (coalesced both directions) ----
// w1T: (d,c) XOR-swizzled (consumed via LDS). w2T: (d,c) PLAIN (consumed from
// global). rw1T/rw2T: (k,d,c) XOR-swizzled (consumed via LDS).
__global__ __launch_bounds__(256) void k_prep(
    const float* __restrict__ w1, const float* __restrict__ w2,
    const float* __restrict__ rw1, const float* __restrict__ rw2,
    unsigned short* __restrict__ w1T, unsigned short* __restrict__ w2T,
    unsigned short* __restrict__ rw1T, unsigned short* __restrict__ rw2T) {
  __shared__ unsigned short L[8320];
  const int tid = threadIdx.x, bid = blockIdx.x;
  if (bid < 16) {
    const bool isw1 = (bid < 8);
    const float* src = isw1 ? w1 : w2;
    unsigned short* dst = isw1 ? w1T : w2T;
    const int seg = bid & 7; // d rows [seg*16, seg*16+16)
#pragma unroll
    for (int i = 0; i < 8; ++i) {
      int idx = i * 256 + tid; // 0..2047
      int c = idx >> 4, dl = idx & 15;
      L[c * 17 + dl] = f2bf(src[c * 128 + seg * 16 + dl]);
    }
    __syncthreads();
    const int dl = tid >> 4, j = tid & 15;
    const int d = seg * 16 + dl;
    frag_ab v;
#pragma unroll
    for (int i = 0; i < 8; ++i) v[i] = (short)L[(8 * j + i) * 17 + dl];
    const int chunk = isw1 ? (j ^ (d & 15)) : j;
    *(frag_ab*)(dst + d * 128 + (chunk << 3)) = v;
  } else {
    const int k = bid - 16;
#pragma unroll
    for (int i = 0; i < 16; ++i) {
      int idx = i * 256 + tid; // c=idx>>6, d=idx&63
      int c = idx >> 6, d = idx & 63;
      L[c * 65 + d] = f2bf(rw1[k * 4096 + idx]);
      L[4160 + c * 65 + d] = f2bf(rw2[k * 4096 + idx]);
    }
    __syncthreads();
#pragma unroll
    for (int h = 0; h < 2; ++h) {
      int cid = h * 256 + tid; // 0..511
      int d = cid >> 3, j = cid & 7;
      frag_ab v1, v2;
#pragma unroll
      for (int i = 0; i < 8; ++i) {
        v1[i] = (short)L[(8 * j + i) * 65 + d];
        v2[i] = (short)L[4160 + (8 * j + i) * 65 + d];
      }
      int pos = k * 4096 + d * 64 + ((j ^ (d & 7)) << 3);
      *(frag_ab*)(rw1T + pos) = v1;
      *(frag_ab*)(rw2T + pos) = v2;
    }
  }
}

// ---- y = bf16(x) @ w1 + b1 (R4-exact); y is N x 128 bf16 ----
__global__ __launch_bounds__(256) void k_gemm_in(
    const float* __restrict__ x, const unsigned short* __restrict__ w1T,
    const float* __restrict__ b1, unsigned short* __restrict__ y) {
  __shared__ unsigned short sw[16384]; // 32KB
  const int tid = threadIdx.x, lane = tid & 63, w = tid >> 6;
  const int m16 = lane & 15, q = lane >> 4;
#pragma unroll
  for (int r = 0; r < 8; ++r) {
    const int off = (w * 8 + r) * 512 + lane * 8;
    gload_lds16(w1T + off, &sw[off]);
  }
  __syncthreads();
  const int rowbase = blockIdx.x * 128 + w * 32;
  f32x4 acc[2][8] = {};
#pragma unroll
  for (int kk = 0; kk < 4; ++kk) {
    frag_ab a[2];
#pragma unroll
    for (int rt = 0; rt < 2; ++rt) {
      int r0 = rowbase + rt * 16 + m16;
      int rc = r0 < N_PTS ? r0 : N_PTS - 1;
      const float* xp = x + (size_t)rc * 128 + kk * 32 + q * 8;
      float4 f0 = *(const float4*)xp;
      float4 f1 = *(const float4*)(xp + 4);
      frag_ab t;
      t[0] = (short)f2bf(f0.x); t[1] = (short)f2bf(f0.y);
      t[2] = (short)f2bf(f0.z); t[3] = (short)f2bf(f0.w);
      t[4] = (short)f2bf(f1.x); t[5] = (short)f2bf(f1.y);
      t[6] = (short)f2bf(f1.z); t[7] = (short)f2bf(f1.w);
      a[rt] = t;
    }
#pragma unroll
    for (int ct = 0; ct < 8; ++ct) {
      const int d = ct * 16 + m16;
      const int phys = ((kk << 2) | q) ^ m16;
      frag_ab bf = *(const frag_ab*)(&sw[d * 128 + phys * 8]);
      acc[0][ct] = __builtin_amdgcn_mfma_f32_16x16x32_bf16(a[0], bf, acc[0][ct], 0, 0, 0);
      acc[1][ct] = __builtin_amdgcn_mfma_f32_16x16x32_bf16(a[1], bf, acc[1][ct], 0, 0, 0);
    }
  }
#pragma unroll
  for (int ct = 0; ct < 8; ++ct) {
    const int col = ct * 16 + m16;
    const float bias = b1[col];
#pragma unroll
    for (int rt = 0; rt < 2; ++rt)
#pragma unroll
      for (int j = 0; j < 4; ++j) {
        int r = rowbase + rt * 16 + q * 4 + j;
        if (r < N_PTS) y[(size_t)r * 128 + col] = f2bf(acc[rt][ct][j] + bias);
      }
  }
}

// ---- conv1 (R4-exact): r1 = relu(sconv(y[:,:64])) ; feat stride 128 ----
__global__ __launch_bounds__(256) void k_conv1(
    const unsigned short* __restrict__ feat,
    const int* __restrict__ nbr,
    const unsigned short* __restrict__ rwT, const float* __restrict__ rb,
    unsigned short* __restrict__ out) {
  __shared__ unsigned short sw[2][4096];
  const int tid = threadIdx.x, lane = tid & 63, w = tid >> 6;
  const int m16 = lane & 15, q = lane >> 4;
  const int rowbase = blockIdx.x * 128 + w * 32;
  const int p0 = rowbase + m16, p1 = p0 + 16;
  const bool v0 = p0 < N_PTS, v1 = p1 < N_PTS;
  const int s0 = w * 1024 + lane * 8;
  const int s1 = s0 + 512;
  const int fstride = 128;

  int i0r[2], i1r[2];
  i0r[0] = v0 ? nbr[p0] : -1;
  i1r[0] = v1 ? nbr[p1] : -1;
  i0r[1] = v0 ? nbr[N_PTS + p0] : -1;
  i1r[1] = v1 ? nbr[N_PTS + p1] : -1;

  frag_ab A[2][2][2];
#pragma unroll
  for (int a = 0; a < 2; ++a)
#pragma unroll
    for (int b = 0; b < 2; ++b)
#pragma unroll
      for (int c = 0; c < 2; ++c) A[a][b][c] = ZFRAG;

  {
    gload_lds16(rwT + s0, &sw[0][s0]);
    gload_lds16(rwT + s1, &sw[0][s1]);
    if (i0r[0] >= 0) {
      const unsigned short* fp = feat + (size_t)i0r[0] * fstride + q * 8;
      A[0][0][0] = *(const frag_ab*)fp; A[0][0][1] = *(const frag_ab*)(fp + 32);
    }
    if (i1r[0] >= 0) {
      const unsigned short* fp = feat + (size_t)i1r[0] * fstride + q * 8;
      A[0][1][0] = *(const frag_ab*)fp; A[0][1][1] = *(const frag_ab*)(fp + 32);
    }
  }
  __syncthreads();

  f32x4 acc[2][4] = {};
#pragma unroll
  for (int k = 0; k < 27; ++k) {
    const int b = k & 1;
    if (k + 1 < 27) {
      const unsigned short* src = rwT + ((k + 1) << 12);
      gload_lds16(src + s0, &sw[b ^ 1][s0]);
      gload_lds16(src + s1, &sw[b ^ 1][s1]);
      const int n = (k + 1) & 1;
      int j0 = i0r[n], j1 = i1r[n];
      A[n][0][0] = ZFRAG; A[n][0][1] = ZFRAG; A[n][1][0] = ZFRAG; A[n][1][1] = ZFRAG;
      if (j0 >= 0) {
        const unsigned short* fp = feat + (size_t)j0 * fstride + q * 8;
        A[n][0][0] = *(const frag_ab*)fp; A[n][0][1] = *(const frag_ab*)(fp + 32);
      }
      if (j1 >= 0) {
        const unsigned short* fp = feat + (size_t)j1 * fstride + q * 8;
        A[n][1][0] = *(const frag_ab*)fp; A[n][1][1] = *(const frag_ab*)(fp + 32);
      }
    }
    if (k + 2 < 27) {
      i0r[k & 1] = v0 ? nbr[(k + 2) * N_PTS + p0] : -1;
      i1r[k & 1] = v1 ? nbr[(k + 2) * N_PTS + p1] : -1;
    }
#pragma unroll
    for (int kk = 0; kk < 2; ++kk)
#pragma unroll
      for (int ct = 0; ct < 4; ++ct) {
        const int d = ct * 16 + m16;
        const int phys = ((kk << 2) | q) ^ (m16 & 7);
        frag_ab bf = *(const frag_ab*)(&sw[b][d * 64 + phys * 8]);
        acc[0][ct] = __builtin_amdgcn_mfma_f32_16x16x32_bf16(A[b][0][kk], bf, acc[0][ct], 0, 0, 0);
        acc[1][ct] = __builtin_amdgcn_mfma_f32_16x16x32_bf16(A[b][1][kk], bf, acc[1][ct], 0, 0, 0);
      }
    __syncthreads();
  }

#pragma unroll
  for (int ct = 0; ct < 4; ++ct) {
    const int col = ct * 16 + m16;
    const float bias = rb[col];
#pragma unroll
    for (int rt = 0; rt < 2; ++rt)
#pragma unroll
      for (int j = 0; j < 4; ++j) {
        const int r = rowbase + rt * 16 + q * 4 + j;
        if (r < N_PTS) {
          float v = acc[rt][ct][j] + bias;
          v = v > 0.f ? v : 0.f;
          out[(size_t)r * 64 + col] = f2bf(v);
        }
      }
  }
}

// ---- conv2 FUSED: z = relu(sconv(r1)) + 2*y[:,:64]; out = x + [z|y[:,64:]]@w2+b2 ----
// conv part identical to R4 (feat=r1, stride 64). Epilogue: z C-layout -> LDS
// (stride 72, wave-private) -> A-layout; B-frags from global w2T (plain, L1-hot).
__global__ __launch_bounds__(256) void k_conv2_fused(
    const unsigned short* __restrict__ feat, // r1, stride 64
    const int* __restrict__ nbr,
    const unsigned short* __restrict__ rwT, const float* __restrict__ rb,
    const unsigned short* __restrict__ y,    // N x 128
    const float* __restrict__ x, const unsigned short* __restrict__ w2T,
    const float* __restrict__ b2, float* __restrict__ out) {
  __shared__ unsigned short sw[2][4096]; // 16KB ping-pong
  __shared__ unsigned short zt[128 * 72]; // 18KB z-tile, +8 pad vs 64
  const int tid = threadIdx.x, lane = tid & 63, w = tid >> 6;
  const int m16 = lane & 15, q = lane >> 4;
  const int rowbase = blockIdx.x * 128 + w * 32;
  const int p0 = rowbase + m16, p1 = p0 + 16;
  const bool v0 = p0 < N_PTS, v1 = p1 < N_PTS;
  const int s0 = w * 1024 + lane * 8;
  const int s1 = s0 + 512;
  const int fstride = 64;

  int i0r[2], i1r[2];
  i0r[0] = v0 ? nbr[p0] : -1;
  i1r[0] = v1 ? nbr[p1] : -1;
  i0r[1] = v0 ? nbr[N_PTS + p0] : -1;
  i1r[1] = v1 ? nbr[N_PTS + p1] : -1;

  frag_ab A[2][2][2];
#pragma unroll
  for (int a = 0; a < 2; ++a)
#pragma unroll
    for (int b = 0; b < 2; ++b)
#pragma unroll
      for (int c = 0; c < 2; ++c) A[a][b][c] = ZFRAG;

  {
    gload_lds16(rwT + s0, &sw[0][s0]);
    gload_lds16(rwT + s1, &sw[0][s1]);
    if (i0r[0] >= 0) {
      const unsigned short* fp = feat + (size_t)i0r[0] * fstride + q * 8;
      A[0][0][0] = *(const frag_ab*)fp; A[0][0][1] = *(const frag_ab*)(fp + 32);
    }
    if (i1r[0] >= 0) {
      const unsigned short* fp = feat + (size_t)i1r[0] * fstride + q * 8;
      A[0][1][0] = *(const frag_ab*)fp; A[0][1][1] = *(const frag_ab*)(fp + 32);
    }
  }
  __syncthreads();

  f32x4 acc[2][4] = {};
#pragma unroll
  for (int k = 0; k < 27; ++k) {
    const int b = k & 1;
    if (k + 1 < 27) {
      const unsigned short* src = rwT + ((k + 1) << 12);
      gload_lds16(src + s0, &sw[b ^ 1][s0]);
      gload_lds16(src + s1, &sw[b ^ 1][s1]);
      const int n = (k + 1) & 1;
      int j0 = i0r[n], j1 = i1r[n];
      A[n][0][0] = ZFRAG; A[n][0][1] = ZFRAG; A[n][1][0] = ZFRAG; A[n][1][1] = ZFRAG;
      if (j0 >= 0) {
        const unsigned short* fp = feat + (size_t)j0 * fstride + q * 8;
        A[n][0][0] = *(const frag_ab*)fp; A[n][0][1] = *(const frag_ab*)(fp + 32);
      }
      if (j1 >= 0) {
        const unsigned short* fp = feat + (size_t)j1 * fstride + q * 8;
        A[n][1][0] = *(const frag_ab*)fp; A[n][1][1] = *(const frag_ab*)(fp + 32);
      }
    }
    if (k + 2 < 27) {
      i0r[k & 1] = v0 ? nbr[(k + 2) * N_PTS + p0] : -1;
      i1r[k & 1] = v1 ? nbr[(k + 2) * N_PTS + p1] : -1;
    }
#pragma unroll
    for (int kk = 0; kk < 2; ++kk)
#pragma unroll
      for (int ct = 0; ct < 4; ++ct) {
        const int d = ct * 16 + m16;
        const int phys = ((kk << 2) | q) ^ (m16 & 7);
        frag_ab bf = *(const frag_ab*)(&sw[b][d * 64 + phys * 8]);
        acc[0][ct] = __builtin_amdgcn_mfma_f32_16x16x32_bf16(A[b][0][kk], bf, acc[0][ct], 0, 0, 0);
        acc[1][ct] = __builtin_amdgcn_mfma_f32_16x16x32_bf16(A[b][1][kk], bf, acc[1][ct], 0, 0, 0);
      }
    __syncthreads();
  }

  // ---- epilogue part 1: z = relu(acc + rb) + 2*y[:, :64] -> wave-private LDS ----
#pragma unroll
  for (int ct = 0; ct < 4; ++ct) {
    const int col = ct * 16 + m16;
    const float bias = rb[col];
#pragma unroll
    for (int rt = 0; rt < 2; ++rt)
#pragma unroll
      for (int j = 0; j < 4; ++j) {
        const int lr = w * 32 + rt * 16 + q * 4 + j; // local row in block
        const int r = rowbase + rt * 16 + q * 4 + j;
        float v = acc[rt][ct][j] + bias;
        v = v > 0.f ? v : 0.f;
        float rv = (r < N_PTS) ? bf2f(y[(size_t)r * 128 + col]) : 0.f;
        zt[lr * 72 + col] = f2bf(v + 2.f * rv);
      }
  }
  // no barrier: each wave reads only its own zt rows (compiler inserts lgkmcnt)

  // ---- epilogue part 2: out = x + [z | y[:,64:]] @ w2 + b2 ----
  frag_ab az[2][2]; // [kk][rt] from zt (K 0..63)
#pragma unroll
  for (int kk = 0; kk < 2; ++kk)
#pragma unroll
    for (int rt = 0; rt < 2; ++rt) {
      const int lr = w * 32 + rt * 16 + m16;
      az[kk][rt] = *(const frag_ab*)(&zt[lr * 72 + kk * 32 + q * 8]);
    }
  frag_ab ay[2][2]; // [kk][rt] from y[:,64:] (K 64..127)
#pragma unroll
  for (int kk = 0; kk < 2; ++kk)
#pragma unroll
    for (int rt = 0; rt < 2; ++rt) {
      const int r0 = rowbase + rt * 16 + m16;
      const int rc = r0 < N_PTS ? r0 : N_PTS - 1;
      ay[kk][rt] = *(const frag_ab*)(y + (size_t)rc * 128 + 64 + kk * 32 + q * 8);
    }
  f32x4 acc2[2][8] = {};
#pragma unroll
  for (int kk = 0; kk < 4; ++kk) {
    frag_ab a0 = (kk < 2) ? az[kk][0] : ay[kk - 2][0];
    frag_ab a1 = (kk < 2) ? az[kk][1] : ay[kk - 2][1];
#pragma unroll
    for (int ct = 0; ct < 8; ++ct) {
      const int d = ct * 16 + m16;
      frag_ab bf = *(const frag_ab*)(w2T + (size_t)d * 128 + kk * 32 + q * 8);
      acc2[0][ct] = __builtin_amdgcn_mfma_f32_16x16x32_bf16(a0, bf, acc2[0][ct], 0, 0, 0);
      acc2[1][ct] = __builtin_amdgcn_mfma_f32_16x16x32_bf16(a1, bf, acc2[1][ct], 0, 0, 0);
    }
  }
#pragma unroll
  for (int ct = 0; ct < 8; ++ct) {
    const int col = ct * 16 + m16;
    const float bias = b2[col];
#pragma unroll
    for (int rt = 0; rt < 2; ++rt)
#pragma unroll
      for (int j = 0; j < 4; ++j) {
        const int r = rowbase + rt * 16 + q * 4 + j;
        if (r < N_PTS) {
          size_t o = (size_t)r * 128 + col;
          out[o] = acc2[rt][ct][j] + bias + x[o];
        }
      }
  }
}

extern "C" void kernel_launch(void* const* d_in, const int* in_sizes, int n_in,
                              void* d_out, int out_size, void* d_ws, size_t ws_size,
                              hipStream_t stream) {
  const float* x   = (const float*)d_in[0];
  const float* w1  = (const float*)d_in[1];
  const float* b1  = (const float*)d_in[2];
  const float* w2  = (const float*)d_in[3];
  const float* b2  = (const float*)d_in[4];
  const float* rw1 = (const float*)d_in[5];
  const float* rb1 = (const float*)d_in[6];
  const float* rw2 = (const float*)d_in[7];
  const float* rb2 = (const float*)d_in[8];
  const int* nbr = (const int*)d_in[9];
  float* out = (float*)d_out;

  char* ws = (char*)d_ws;
  unsigned short* w1T  = (unsigned short*)(ws);                       // 32 KB
  unsigned short* w2T  = (unsigned short*)(ws + 32768);               // 32 KB
  unsigned short* rw1T = (unsigned short*)(ws + 65536);               // 216 KB
  unsigned short* rw2T = (unsigned short*)(ws + 286720);              // 216 KB
  unsigned short* y    = (unsigned short*)(ws + 507904);              // 25.6 MB
  unsigned short* r1   = (unsigned short*)(ws + 507904 + 25600000);   // 12.8 MB

  k_prep<<<43, 256, 0, stream>>>(w1, w2, rw1, rw2, w1T, w2T, rw1T, rw2T);
  k_gemm_in<<<NBLK128, 256, 0, stream>>>(x, w1T, b1, y);
  k_conv1<<<NBLK128, 256, 0, stream>>>(y, nbr, rw1T, rb1, r1);
  k_conv2_fused<<<NBLK128, 256, 0, stream>>>(r1, nbr, rw2T, rb2, y, x, w2T, b2, out);
}